// Round 1
// baseline (1528.666 us; speedup 1.0000x reference)
//
#include <hip/hip_runtime.h>

#define B_ 4
#define C_ 64
#define H_ 160
#define W_ 160
#define HW_ (H_*W_)

// ---------------- weight transpose: w[oc][r] -> wt[r][oc], r = ic*9+k ----------------
__global__ void wtrans_kernel(const float* __restrict__ w, float* __restrict__ wt,
                              int OC, int CINK) {
  int i = blockIdx.x * 256 + threadIdx.x;
  if (i >= OC * CINK) return;
  int oc = i / CINK, r = i % CINK;
  wt[(size_t)r * OC + oc] = w[i];
}

// ---------------- direct 3x3 SAME conv, NCHW, weights pre-transposed -----------------
// in channels CIN split across two pointers at csplit (for the concat input).
template<int OCB, int CIN, bool RELU, bool BIAS>
__global__ __launch_bounds__(256) void conv3x3_kernel(
    const float* __restrict__ in0, const float* __restrict__ in1, int csplit,
    const float* __restrict__ wt, const float* __restrict__ bias,
    float* __restrict__ out, int OC) {
  const int tile = blockIdx.x;
  const int tx0 = (tile % (W_ / 32)) * 32;
  const int ty0 = (tile / (W_ / 32)) * 8;
  const int ocg = blockIdx.y;
  const int b   = blockIdx.z;
  const int tx = threadIdx.x & 31, ty = threadIdx.x >> 5;
  const int x = tx0 + tx, y = ty0 + ty;

  int   idx[9];
  float msk[9];
#pragma unroll
  for (int k = 0; k < 9; k++) {
    int yy = y + k / 3 - 1, xx = x + (k % 3) - 1;
    bool v = (yy >= 0) & (yy < H_) & (xx >= 0) & (xx < W_);
    int yc = min(max(yy, 0), H_ - 1), xc = min(max(xx, 0), W_ - 1);
    idx[k] = yc * W_ + xc;
    msk[k] = v ? 1.f : 0.f;
  }

  float acc[OCB];
#pragma unroll
  for (int i = 0; i < OCB; i++) acc[i] = BIAS ? bias[ocg * OCB + i] : 0.f;

  for (int ic = 0; ic < CIN; ic++) {
    const float* ip = (ic < csplit)
        ? in0 + ((size_t)b * csplit + ic) * HW_
        : in1 + ((size_t)b * (CIN - csplit) + (ic - csplit)) * HW_;
    float v[9];
#pragma unroll
    for (int k = 0; k < 9; k++) v[k] = ip[idx[k]] * msk[k];
    const float* wp = wt + (size_t)ic * 9 * OC + ocg * OCB;
#pragma unroll
    for (int k = 0; k < 9; k++) {
#pragma unroll
      for (int oc = 0; oc < OCB; oc++)
        acc[oc] += v[k] * wp[k * OC + oc];
    }
  }

  float* op = out + ((size_t)b * OC + ocg * OCB) * HW_ + (size_t)y * W_ + x;
#pragma unroll
  for (int oc = 0; oc < OCB; oc++) {
    float r = acc[oc];
    if (RELU) r = fmaxf(r, 0.f);
    op[(size_t)oc * HW_] = r;
  }
}

// ---------------- deformable conv: hr(64ch) + offsets(18ch) -> out(64ch) -------------
// weights pre-transposed to wt[(c*9+k)*64 + oc]
__global__ __launch_bounds__(256) void deform_kernel(
    const float* __restrict__ hr, const float* __restrict__ off,
    const float* __restrict__ wt, float* __restrict__ out) {
  const int tile = blockIdx.x;
  const int tx0 = (tile % (W_ / 32)) * 32, ty0 = (tile / (W_ / 32)) * 8;
  const int ocg = blockIdx.y;   // 2 groups of 32 oc
  const int b   = blockIdx.z;
  const int tx = threadIdx.x & 31, ty = threadIdx.x >> 5;
  const int x = tx0 + tx, y = ty0 + ty;
  const int pix = y * W_ + x;

  float acc[32];
#pragma unroll
  for (int i = 0; i < 32; i++) acc[i] = 0.f;

  const float* hrb = hr + (size_t)b * C_ * HW_;

#pragma unroll
  for (int k = 0; k < 9; k++) {
    float dy = off[((size_t)b * 18 + 2 * k) * HW_ + pix];
    float dx = off[((size_t)b * 18 + 2 * k + 1) * HW_ + pix];
    float py = (float)(y + k / 3 - 1) + dy;
    float px = (float)(x + (k % 3) - 1) + dx;
    float y0f = floorf(py), x0f = floorf(px);
    float wy = py - y0f, wx = px - x0f;
    int y0 = (int)y0f, x0 = (int)x0f;
    int y1 = y0 + 1, x1 = x0 + 1;
    bool vy0 = (y0 >= 0) & (y0 < H_), vy1 = (y1 >= 0) & (y1 < H_);
    bool vx0 = (x0 >= 0) & (x0 < W_), vx1 = (x1 >= 0) & (x1 < W_);
    int y0c = min(max(y0, 0), H_ - 1), y1c = min(max(y1, 0), H_ - 1);
    int x0c = min(max(x0, 0), W_ - 1), x1c = min(max(x1, 0), W_ - 1);
    int i00 = y0c * W_ + x0c, i01 = y0c * W_ + x1c;
    int i10 = y1c * W_ + x0c, i11 = y1c * W_ + x1c;
    float w00 = (1.f - wy) * (1.f - wx) * ((vy0 & vx0) ? 1.f : 0.f);
    float w01 = (1.f - wy) * wx         * ((vy0 & vx1) ? 1.f : 0.f);
    float w10 = wy * (1.f - wx)         * ((vy1 & vx0) ? 1.f : 0.f);
    float w11 = wy * wx                 * ((vy1 & vx1) ? 1.f : 0.f);

    for (int c = 0; c < C_; c++) {
      const float* p = hrb + (size_t)c * HW_;
      float samp = p[i00] * w00 + p[i01] * w01 + p[i10] * w10 + p[i11] * w11;
      const float* wq = wt + ((size_t)c * 9 + k) * C_ + ocg * 32;
#pragma unroll
      for (int oc = 0; oc < 32; oc++) acc[oc] += samp * wq[oc];
    }
  }

  float* op = out + ((size_t)b * C_ + ocg * 32) * HW_ + pix;
#pragma unroll
  for (int oc = 0; oc < 32; oc++) op[(size_t)oc * HW_] = acc[oc];
}

extern "C" void kernel_launch(void* const* d_in, const int* in_sizes, int n_in,
                              void* d_out, int out_size, void* d_ws, size_t ws_size,
                              hipStream_t stream) {
  const float* lr = (const float*)d_in[0];
  const float* hr = (const float*)d_in[1];
  const float* w1 = (const float*)d_in[2];
  const float* b1 = (const float*)d_in[3];
  const float* w2 = (const float*)d_in[4];
  const float* b2 = (const float*)d_in[5];
  const float* wo = (const float*)d_in[6];
  const float* wd = (const float*)d_in[7];
  float* out = (float*)d_out;

  float* h1   = (float*)d_ws;                       // 4*128*160*160
  float* h2   = h1  + (size_t)B_ * 128 * HW_;       // 4*128*160*160
  float* offb = h2  + (size_t)B_ * 128 * HW_;       // 4*18*160*160
  float* wt1  = offb + (size_t)B_ * 18 * HW_;       // 128*128*9
  float* wt2  = wt1 + 128 * 128 * 9;                // 128*128*9
  float* wto  = wt2 + 128 * 128 * 9;                // 18*128*9
  float* wtd  = wto + 18 * 128 * 9;                 // 64*64*9

  dim3 blk(256);
  wtrans_kernel<<<dim3((128 * 128 * 9 + 255) / 256), blk, 0, stream>>>(w1, wt1, 128, 128 * 9);
  wtrans_kernel<<<dim3((128 * 128 * 9 + 255) / 256), blk, 0, stream>>>(w2, wt2, 128, 128 * 9);
  wtrans_kernel<<<dim3((18 * 128 * 9 + 255) / 256), blk, 0, stream>>>(wo, wto, 18, 128 * 9);
  wtrans_kernel<<<dim3((64 * 64 * 9 + 255) / 256), blk, 0, stream>>>(wd, wtd, 64, 64 * 9);

  // conv1: concat(lr,hr) -> h1, relu+bias
  conv3x3_kernel<32, 128, true, true><<<dim3(100, 4, B_), blk, 0, stream>>>(
      lr, hr, 64, wt1, b1, h1, 128);
  // conv2: h1 -> h2, relu+bias
  conv3x3_kernel<32, 128, true, true><<<dim3(100, 4, B_), blk, 0, stream>>>(
      h1, h1, 128, wt2, b2, h2, 128);
  // offset conv: h2 -> offb (no bias, no relu)
  conv3x3_kernel<18, 128, false, false><<<dim3(100, 1, B_), blk, 0, stream>>>(
      h2, h2, 128, wto, nullptr, offb, 18);
  // deformable conv
  deform_kernel<<<dim3(100, 2, B_), blk, 0, stream>>>(hr, offb, wtd, out);
}

// Round 3
// 616.736 us; speedup vs baseline: 2.4786x; 2.4786x over previous
//
#include <hip/hip_runtime.h>

#define H_ 160
#define W_ 160
#define HW_ (H_*W_)
#define B_ 4

typedef _Float16 f16x8 __attribute__((ext_vector_type(8)));
typedef float f32x4 __attribute__((ext_vector_type(4)));

__device__ __forceinline__ unsigned short f2h(float f) {
  _Float16 h = (_Float16)f;
  return *reinterpret_cast<unsigned short*>(&h);
}

// ============ prep: CHW fp32 (lr,hr) -> cat HWC fp16 [pix][128], hr HWC fp32 [pix][64]
__global__ __launch_bounds__(256) void prep_inputs(
    const float* __restrict__ lr, const float* __restrict__ hr,
    unsigned short* __restrict__ cat, float* __restrict__ hrh) {
  __shared__ float t0[64][65];
  const int b = blockIdx.z;
  const int px0 = blockIdx.x * 64;
  const int t = threadIdx.x;
  const int cc = t >> 6, lp = t & 63;

  // ---- lr pass -> cat channels 0..63
#pragma unroll
  for (int r = 0; r < 16; r++) {
    int c = r * 4 + cc;
    t0[lp][c] = lr[((size_t)b * 64 + c) * HW_ + px0 + lp];
  }
  __syncthreads();
  {
    int px = t >> 2, seg = t & 3;
    size_t pix = (size_t)b * HW_ + px0 + px;
    unsigned short* dst = cat + pix * 128 + seg * 16;
#pragma unroll
    for (int q = 0; q < 4; q++) {
      ushort4 o;
      o.x = f2h(t0[px][seg * 16 + q * 4 + 0]);
      o.y = f2h(t0[px][seg * 16 + q * 4 + 1]);
      o.z = f2h(t0[px][seg * 16 + q * 4 + 2]);
      o.w = f2h(t0[px][seg * 16 + q * 4 + 3]);
      *reinterpret_cast<ushort4*>(dst + q * 4) = o;
    }
  }
  __syncthreads();
  // ---- hr pass -> cat channels 64..127 + hrh fp32
#pragma unroll
  for (int r = 0; r < 16; r++) {
    int c = r * 4 + cc;
    t0[lp][c] = hr[((size_t)b * 64 + c) * HW_ + px0 + lp];
  }
  __syncthreads();
  {
    int px = t >> 2, seg = t & 3;
    size_t pix = (size_t)b * HW_ + px0 + px;
    unsigned short* dst = cat + pix * 128 + 64 + seg * 16;
    float* fdst = hrh + pix * 64 + seg * 16;
#pragma unroll
    for (int q = 0; q < 4; q++) {
      float v0 = t0[px][seg * 16 + q * 4 + 0];
      float v1 = t0[px][seg * 16 + q * 4 + 1];
      float v2 = t0[px][seg * 16 + q * 4 + 2];
      float v3 = t0[px][seg * 16 + q * 4 + 3];
      ushort4 o; o.x = f2h(v0); o.y = f2h(v1); o.z = f2h(v2); o.w = f2h(v3);
      *reinterpret_cast<ushort4*>(dst + q * 4) = o;
      float4 f; f.x = v0; f.y = v1; f.z = v2; f.w = v3;
      *reinterpret_cast<float4*>(fdst + q * 4) = f;
    }
  }
}

// ============ weight prep: w[oc][ic][3][3] fp32 -> wtb[k][ocp][ic] fp16 (zero-pad oc)
__global__ void wprep_b(const float* __restrict__ w, unsigned short* __restrict__ out,
                        int OC, int OCP, int CIN) {
  int i = blockIdx.x * 256 + threadIdx.x;
  int tot = 9 * OCP * CIN;
  if (i >= tot) return;
  int k = i / (OCP * CIN);
  int r = i % (OCP * CIN);
  int oc = r / CIN, ic = r % CIN;
  float v = (oc < OC) ? w[((size_t)(oc * CIN + ic)) * 9 + k] : 0.f;
  out[i] = f2h(v);
}

// deform weights: wd[oc][c][3][3] fp32 -> wdt[k][c][oc] fp32
__global__ void wprep_d(const float* __restrict__ w, float* __restrict__ out) {
  int i = blockIdx.x * 256 + threadIdx.x;
  if (i >= 9 * 64 * 64) return;
  int k = i / 4096;
  int r = i % 4096;
  int c = r / 64, oc = r % 64;
  out[i] = w[((size_t)(oc * 64 + c)) * 9 + k];
}

// ============ implicit-GEMM conv3x3, HWC fp16 in, 16x16x32 f16 MFMA
// A = weights [k][MT][128ic] fp16 ; B = shifted input [pix][ic] fp16 (B^T layout)
// OUTK 0: fp16 HWC out + bias + relu ; OUTK 1: fp32 [pix][18] out (18 of 32 oc rows)
template<int MFR, int NFR, int WM, int WN, int OUTK>
__global__ __launch_bounds__(256) void convk(
    const unsigned short* __restrict__ xin,   // [b][25600][128] fp16
    const unsigned short* __restrict__ wtb,   // [9][MT][128] fp16
    const float* __restrict__ bias,
    unsigned short* __restrict__ obf, float* __restrict__ of32) {
  constexpr int MT = WM * MFR * 16;
  constexpr int NT = WN * NFR * 16;
  constexpr int TY = NT / 32;
  constexpr int LROW = 40;  // padded row (ushorts): 32 ic + 8 pad
  constexpr int BCH = NT / 128;
  __shared__ unsigned short lds[2 * (MT + NT) * LROW];

  const int t = threadIdx.x, lane = t & 63, wid = t >> 6;
  const int wm = wid / WN, wn = wid % WN;
  const int b = blockIdx.z;
  const int tx0 = (blockIdx.x % 5) * 32;
  const int ty0 = (blockIdx.x / 5) * TY;
  const size_t xbase = (size_t)b * HW_ * 128;

  uint4 rA[2];
  uint4 rB[2 * BCH];

  auto loadStage = [&](int s) {
    const int k = s >> 2, cc = s & 3;
    const int kdy = k / 3 - 1, kdx = k % 3 - 1;
    if (t < MT * 2) {
      int row = t >> 1, half = t & 1;
      const uint4* src = reinterpret_cast<const uint4*>(
          wtb + ((size_t)(k * MT + row) * 128 + cc * 32 + half * 16));
      rA[0] = src[0]; rA[1] = src[1];
    }
#pragma unroll
    for (int i = 0; i < BCH; i++) {
      int ch = t + i * 256;
      int row = ch >> 1, half = ch & 1;
      int psy = row >> 5, psx = row & 31;
      int yy = ty0 + psy + kdy, xx = tx0 + psx + kdx;
      if (yy >= 0 && yy < H_ && xx >= 0 && xx < W_) {
        const uint4* src = reinterpret_cast<const uint4*>(
            xin + xbase + ((size_t)(yy * W_ + xx) * 128 + cc * 32 + half * 16));
        rB[2 * i] = src[0]; rB[2 * i + 1] = src[1];
      } else {
        uint4 z; z.x = z.y = z.z = z.w = 0u;
        rB[2 * i] = z; rB[2 * i + 1] = z;
      }
    }
  };
  auto writeStage = [&](int q) {
    unsigned short* A = &lds[q * (MT + NT) * LROW];
    unsigned short* Bl = A + MT * LROW;
    if (t < MT * 2) {
      int row = t >> 1, half = t & 1;
      *reinterpret_cast<uint4*>(A + row * LROW + half * 16) = rA[0];
      *reinterpret_cast<uint4*>(A + row * LROW + half * 16 + 8) = rA[1];
    }
#pragma unroll
    for (int i = 0; i < BCH; i++) {
      int ch = t + i * 256;
      int row = ch >> 1, half = ch & 1;
      *reinterpret_cast<uint4*>(Bl + row * LROW + half * 16) = rB[2 * i];
      *reinterpret_cast<uint4*>(Bl + row * LROW + half * 16 + 8) = rB[2 * i + 1];
    }
  };

  f32x4 acc[MFR][NFR];
#pragma unroll
  for (int m = 0; m < MFR; m++)
#pragma unroll
    for (int n = 0; n < NFR; n++) acc[m][n] = (f32x4)(0.f);

  loadStage(0);
  writeStage(0);

  for (int s = 0; s < 36; s++) {
    __syncthreads();
    if (s < 35) loadStage(s + 1);
    const unsigned short* A = &lds[(s & 1) * (MT + NT) * LROW];
    const unsigned short* Bl = A + MT * LROW;
    f16x8 af[MFR], bf[NFR];
#pragma unroll
    for (int m = 0; m < MFR; m++)
      af[m] = *reinterpret_cast<const f16x8*>(
          A + ((wm * MFR + m) * 16 + (lane & 15)) * LROW + (lane >> 4) * 8);
#pragma unroll
    for (int n = 0; n < NFR; n++)
      bf[n] = *reinterpret_cast<const f16x8*>(
          Bl + ((wn * NFR + n) * 16 + (lane & 15)) * LROW + (lane >> 4) * 8);
#pragma unroll
    for (int m = 0; m < MFR; m++)
#pragma unroll
      for (int n = 0; n < NFR; n++)
        acc[m][n] = __builtin_amdgcn_mfma_f32_16x16x32_f16(af[m], bf[n], acc[m][n], 0, 0, 0);
    __syncthreads();
    if (s < 35) writeStage((s + 1) & 1);
  }

  if constexpr (OUTK == 0) {
#pragma unroll
    for (int m = 0; m < MFR; m++) {
      int ocb = (wm * MFR + m) * 16 + ((lane >> 4) << 2);
      float4 bv = *reinterpret_cast<const float4*>(bias + ocb);
#pragma unroll
      for (int n = 0; n < NFR; n++) {
        int pxl = (wn * NFR + n) * 16 + (lane & 15);
        int psy = pxl >> 5, psx = pxl & 31;
        size_t pixg = (size_t)b * HW_ + (size_t)(ty0 + psy) * W_ + tx0 + psx;
        ushort4 o;
        o.x = f2h(fmaxf(acc[m][n][0] + bv.x, 0.f));
        o.y = f2h(fmaxf(acc[m][n][1] + bv.y, 0.f));
        o.z = f2h(fmaxf(acc[m][n][2] + bv.z, 0.f));
        o.w = f2h(fmaxf(acc[m][n][3] + bv.w, 0.f));
        *reinterpret_cast<ushort4*>(obf + pixg * 128 + ocb) = o;
      }
    }
  } else {
#pragma unroll
    for (int m = 0; m < MFR; m++) {
      int ocb = (wm * MFR + m) * 16 + ((lane >> 4) << 2);
#pragma unroll
      for (int n = 0; n < NFR; n++) {
        int pxl = (wn * NFR + n) * 16 + (lane & 15);
        int psy = pxl >> 5, psx = pxl & 31;
        size_t pixg = (size_t)b * HW_ + (size_t)(ty0 + psy) * W_ + tx0 + psx;
#pragma unroll
        for (int j = 0; j < 4; j++) {
          int oc = ocb + j;
          if (oc < 18) of32[pixg * 18 + oc] = acc[m][n][j];
        }
      }
    }
  }
}

// ============ deformable conv: hr HWC fp32, offsets HWC fp32, weights [k][c][oc]
__global__ __launch_bounds__(256) void deform2(
    const float* __restrict__ hrh, const float* __restrict__ off,
    const float* __restrict__ wdt, float* __restrict__ out) {
  const int b = blockIdx.z;
  const int tile = blockIdx.x;
  const int tx0 = (tile % 5) * 32, ty0 = (tile / 5) * 8;
  const int t = threadIdx.x;
  const int psx = t & 31, psy = t >> 5;
  const int x = tx0 + psx, y = ty0 + psy;
  const int pix = y * W_ + x;

  float acc[64];
#pragma unroll
  for (int i = 0; i < 64; i++) acc[i] = 0.f;

  const float* hb = hrh + (size_t)b * HW_ * 64;
  const float* ob = off + ((size_t)b * HW_ + pix) * 18;

#pragma unroll 1
  for (int k = 0; k < 9; k++) {
    float dy = ob[2 * k];
    float dx = ob[2 * k + 1];
    float pyf = (float)(y + k / 3 - 1) + dy;
    float pxf = (float)(x + k % 3 - 1) + dx;
    float y0f = floorf(pyf), x0f = floorf(pxf);
    float wy = pyf - y0f, wx = pxf - x0f;
    int y0 = (int)y0f, x0i = (int)x0f;
    int y1 = y0 + 1, x1 = x0i + 1;
    bool vy0 = (y0 >= 0) & (y0 < H_), vy1 = (y1 >= 0) & (y1 < H_);
    bool vx0 = (x0i >= 0) & (x0i < W_), vx1 = (x1 >= 0) & (x1 < W_);
    int y0c = min(max(y0, 0), H_ - 1), y1c = min(max(y1, 0), H_ - 1);
    int x0c = min(max(x0i, 0), W_ - 1), x1c = min(max(x1, 0), W_ - 1);
    float w00 = (1.f - wy) * (1.f - wx) * ((vy0 & vx0) ? 1.f : 0.f);
    float w01 = (1.f - wy) * wx * ((vy0 & vx1) ? 1.f : 0.f);
    float w10 = wy * (1.f - wx) * ((vy1 & vx0) ? 1.f : 0.f);
    float w11 = wy * wx * ((vy1 & vx1) ? 1.f : 0.f);
    const float* p00 = hb + (size_t)(y0c * W_ + x0c) * 64;
    const float* p01 = hb + (size_t)(y0c * W_ + x1c) * 64;
    const float* p10 = hb + (size_t)(y1c * W_ + x0c) * 64;
    const float* p11 = hb + (size_t)(y1c * W_ + x1c) * 64;

#pragma unroll 1
    for (int c0 = 0; c0 < 64; c0 += 4) {
      float4 a0 = *reinterpret_cast<const float4*>(p00 + c0);
      float4 a1 = *reinterpret_cast<const float4*>(p01 + c0);
      float4 a2 = *reinterpret_cast<const float4*>(p10 + c0);
      float4 a3 = *reinterpret_cast<const float4*>(p11 + c0);
      float sx = w00 * a0.x + w01 * a1.x + w10 * a2.x + w11 * a3.x;
      float sy = w00 * a0.y + w01 * a1.y + w10 * a2.y + w11 * a3.y;
      float sz = w00 * a0.z + w01 * a1.z + w10 * a2.z + w11 * a3.z;
      float sw = w00 * a0.w + w01 * a1.w + w10 * a2.w + w11 * a3.w;
      const float* wq = wdt + ((size_t)k * 64 + c0) * 64;
#pragma unroll
      for (int oc = 0; oc < 64; oc++) {
        acc[oc] += sx * wq[oc] + sy * wq[64 + oc] + sz * wq[128 + oc] + sw * wq[192 + oc];
      }
    }
  }

  float* op = out + (size_t)b * 64 * HW_ + pix;
#pragma unroll
  for (int oc = 0; oc < 64; oc++) op[(size_t)oc * HW_] = acc[oc];
}

extern "C" void kernel_launch(void* const* d_in, const int* in_sizes, int n_in,
                              void* d_out, int out_size, void* d_ws, size_t ws_size,
                              hipStream_t stream) {
  const float* lr = (const float*)d_in[0];
  const float* hr = (const float*)d_in[1];
  const float* w1 = (const float*)d_in[2];
  const float* b1 = (const float*)d_in[3];
  const float* w2 = (const float*)d_in[4];
  const float* b2 = (const float*)d_in[5];
  const float* wo = (const float*)d_in[6];
  const float* wd = (const float*)d_in[7];
  float* out = (float*)d_out;

  // workspace layout (regions 16B-aligned)
  char* w = (char*)d_ws;
  const size_t REG = 26214400;  // 4*25600*128*2B (= 4*25600*64*4B)
  unsigned short* cat = (unsigned short*)w;          // later reused as h2
  unsigned short* h2  = (unsigned short*)w;
  unsigned short* h1  = (unsigned short*)(w + REG);  // later reused as offsets
  float*          offb = (float*)(w + REG);
  float*          hrh = (float*)(w + 2 * REG);
  char* pD = w + 3 * REG;
  unsigned short* wt1b = (unsigned short*)pD;                    // 9*128*128*2 = 294912
  unsigned short* wt2b = (unsigned short*)(pD + 294912);
  unsigned short* wtob = (unsigned short*)(pD + 2 * 294912);     // 9*32*128*2 = 73728
  float*          wdt  = (float*)(pD + 2 * 294912 + 73728);      // 9*64*64*4 = 147456

  prep_inputs<<<dim3(400, 1, B_), 256, 0, stream>>>(lr, hr, cat, hrh);
  wprep_b<<<dim3((9 * 128 * 128 + 255) / 256), 256, 0, stream>>>(w1, wt1b, 128, 128, 128);
  wprep_b<<<dim3((9 * 128 * 128 + 255) / 256), 256, 0, stream>>>(w2, wt2b, 128, 128, 128);
  wprep_b<<<dim3((9 * 32 * 128 + 255) / 256), 256, 0, stream>>>(wo, wtob, 18, 32, 128);
  wprep_d<<<dim3((9 * 64 * 64 + 255) / 256), 256, 0, stream>>>(wd, wdt);

  // conv1: cat -> h1 (fp16 HWC), bias+relu
  convk<4, 4, 2, 2, 0><<<dim3(200, 1, B_), 256, 0, stream>>>(cat, wt1b, b1, h1, nullptr);
  // conv2: h1 -> h2 (fp16 HWC), bias+relu   (h2 aliases cat, dead after conv1)
  convk<4, 4, 2, 2, 0><<<dim3(200, 1, B_), 256, 0, stream>>>(h1, wt2b, b2, h2, nullptr);
  // offset conv: h2 -> offb fp32 [pix][18]  (offb aliases h1, dead after conv2)
  convk<2, 4, 1, 4, 1><<<dim3(100, 1, B_), 256, 0, stream>>>(h2, wtob, nullptr, nullptr, offb);
  // deformable conv
  deform2<<<dim3(100, 1, B_), 256, 0, stream>>>(hrh, offb, wdt, out);
}

// Round 4
// 495.161 us; speedup vs baseline: 3.0872x; 1.2455x over previous
//
#include <hip/hip_runtime.h>

#define H_ 160
#define W_ 160
#define HW_ (H_*W_)
#define B_ 4

typedef _Float16 f16x8 __attribute__((ext_vector_type(8)));
typedef float f32x4 __attribute__((ext_vector_type(4)));
typedef unsigned short u16x8 __attribute__((ext_vector_type(8)));

__device__ __forceinline__ unsigned short f2h(float f) {
  _Float16 h = (_Float16)f;
  return *reinterpret_cast<unsigned short*>(&h);
}

// ============ prep: CHW fp32 (lr,hr) -> cat HWC fp16 [pix][128], hr HWC fp32 [pix][64]
__global__ __launch_bounds__(256) void prep_inputs(
    const float* __restrict__ lr, const float* __restrict__ hr,
    unsigned short* __restrict__ cat, float* __restrict__ hrh) {
  __shared__ float t0[64][65];
  const int b = blockIdx.z;
  const int px0 = blockIdx.x * 64;
  const int t = threadIdx.x;
  const int cc = t >> 6, lp = t & 63;

#pragma unroll
  for (int r = 0; r < 16; r++) {
    int c = r * 4 + cc;
    t0[lp][c] = lr[((size_t)b * 64 + c) * HW_ + px0 + lp];
  }
  __syncthreads();
  {
    int px = t >> 2, seg = t & 3;
    size_t pix = (size_t)b * HW_ + px0 + px;
    unsigned short* dst = cat + pix * 128 + seg * 16;
#pragma unroll
    for (int q = 0; q < 4; q++) {
      ushort4 o;
      o.x = f2h(t0[px][seg * 16 + q * 4 + 0]);
      o.y = f2h(t0[px][seg * 16 + q * 4 + 1]);
      o.z = f2h(t0[px][seg * 16 + q * 4 + 2]);
      o.w = f2h(t0[px][seg * 16 + q * 4 + 3]);
      *reinterpret_cast<ushort4*>(dst + q * 4) = o;
    }
  }
  __syncthreads();
#pragma unroll
  for (int r = 0; r < 16; r++) {
    int c = r * 4 + cc;
    t0[lp][c] = hr[((size_t)b * 64 + c) * HW_ + px0 + lp];
  }
  __syncthreads();
  {
    int px = t >> 2, seg = t & 3;
    size_t pix = (size_t)b * HW_ + px0 + px;
    unsigned short* dst = cat + pix * 128 + 64 + seg * 16;
    float* fdst = hrh + pix * 64 + seg * 16;
#pragma unroll
    for (int q = 0; q < 4; q++) {
      float v0 = t0[px][seg * 16 + q * 4 + 0];
      float v1 = t0[px][seg * 16 + q * 4 + 1];
      float v2 = t0[px][seg * 16 + q * 4 + 2];
      float v3 = t0[px][seg * 16 + q * 4 + 3];
      ushort4 o; o.x = f2h(v0); o.y = f2h(v1); o.z = f2h(v2); o.w = f2h(v3);
      *reinterpret_cast<ushort4*>(dst + q * 4) = o;
      float4 f; f.x = v0; f.y = v1; f.z = v2; f.w = v3;
      *reinterpret_cast<float4*>(fdst + q * 4) = f;
    }
  }
}

// ============ weight prep: w[oc][ic][3][3] fp32 -> wtb[k][ocp][ic] fp16 (zero-pad oc)
__global__ void wprep_b(const float* __restrict__ w, unsigned short* __restrict__ out,
                        int OC, int OCP, int CIN) {
  int i = blockIdx.x * 256 + threadIdx.x;
  int tot = 9 * OCP * CIN;
  if (i >= tot) return;
  int k = i / (OCP * CIN);
  int r = i % (OCP * CIN);
  int oc = r / CIN, ic = r % CIN;
  float v = (oc < OC) ? w[((size_t)(oc * CIN + ic)) * 9 + k] : 0.f;
  out[i] = f2h(v);
}

// deform weights: wd[oc][c][3][3] fp32 -> wdh[k][oc][c] fp16
__global__ void wprep_d(const float* __restrict__ w, unsigned short* __restrict__ out) {
  int i = blockIdx.x * 256 + threadIdx.x;
  if (i >= 9 * 64 * 64) return;
  int k = i / 4096;
  int r = i % 4096;
  int oc = r >> 6, c = r & 63;
  out[i] = f2h(w[((size_t)(oc * 64 + c)) * 9 + k]);
}

// ============ implicit-GEMM conv3x3, HWC fp16 in, 16x16x32 f16 MFMA
template<int MFR, int NFR, int WM, int WN, int OUTK>
__global__ __launch_bounds__(256) void convk(
    const unsigned short* __restrict__ xin,   // [b][25600][128] fp16
    const unsigned short* __restrict__ wtb,   // [9][MT][128] fp16
    const float* __restrict__ bias,
    unsigned short* __restrict__ obf, float* __restrict__ of32) {
  constexpr int MT = WM * MFR * 16;
  constexpr int NT = WN * NFR * 16;
  constexpr int TY = NT / 32;
  constexpr int LROW = 40;
  constexpr int BCH = NT / 128;
  __shared__ unsigned short lds[2 * (MT + NT) * LROW];

  const int t = threadIdx.x, lane = t & 63, wid = t >> 6;
  const int wm = wid / WN, wn = wid % WN;
  const int b = blockIdx.z;
  const int tx0 = (blockIdx.x % 5) * 32;
  const int ty0 = (blockIdx.x / 5) * TY;
  const size_t xbase = (size_t)b * HW_ * 128;

  uint4 rA[2];
  uint4 rB[2 * BCH];

  auto loadStage = [&](int s) {
    const int k = s >> 2, cc = s & 3;
    const int kdy = k / 3 - 1, kdx = k % 3 - 1;
    if (t < MT * 2) {
      int row = t >> 1, half = t & 1;
      const uint4* src = reinterpret_cast<const uint4*>(
          wtb + ((size_t)(k * MT + row) * 128 + cc * 32 + half * 16));
      rA[0] = src[0]; rA[1] = src[1];
    }
#pragma unroll
    for (int i = 0; i < BCH; i++) {
      int ch = t + i * 256;
      int row = ch >> 1, half = ch & 1;
      int psy = row >> 5, psx = row & 31;
      int yy = ty0 + psy + kdy, xx = tx0 + psx + kdx;
      if (yy >= 0 && yy < H_ && xx >= 0 && xx < W_) {
        const uint4* src = reinterpret_cast<const uint4*>(
            xin + xbase + ((size_t)(yy * W_ + xx) * 128 + cc * 32 + half * 16));
        rB[2 * i] = src[0]; rB[2 * i + 1] = src[1];
      } else {
        uint4 z; z.x = z.y = z.z = z.w = 0u;
        rB[2 * i] = z; rB[2 * i + 1] = z;
      }
    }
  };
  auto writeStage = [&](int q) {
    unsigned short* A = &lds[q * (MT + NT) * LROW];
    unsigned short* Bl = A + MT * LROW;
    if (t < MT * 2) {
      int row = t >> 1, half = t & 1;
      *reinterpret_cast<uint4*>(A + row * LROW + half * 16) = rA[0];
      *reinterpret_cast<uint4*>(A + row * LROW + half * 16 + 8) = rA[1];
    }
#pragma unroll
    for (int i = 0; i < BCH; i++) {
      int ch = t + i * 256;
      int row = ch >> 1, half = ch & 1;
      *reinterpret_cast<uint4*>(Bl + row * LROW + half * 16) = rB[2 * i];
      *reinterpret_cast<uint4*>(Bl + row * LROW + half * 16 + 8) = rB[2 * i + 1];
    }
  };

  f32x4 acc[MFR][NFR];
#pragma unroll
  for (int m = 0; m < MFR; m++)
#pragma unroll
    for (int n = 0; n < NFR; n++) acc[m][n] = (f32x4)(0.f);

  loadStage(0);
  writeStage(0);

  for (int s = 0; s < 36; s++) {
    __syncthreads();
    if (s < 35) loadStage(s + 1);
    const unsigned short* A = &lds[(s & 1) * (MT + NT) * LROW];
    const unsigned short* Bl = A + MT * LROW;
    f16x8 af[MFR], bf[NFR];
#pragma unroll
    for (int m = 0; m < MFR; m++)
      af[m] = *reinterpret_cast<const f16x8*>(
          A + ((wm * MFR + m) * 16 + (lane & 15)) * LROW + (lane >> 4) * 8);
#pragma unroll
    for (int n = 0; n < NFR; n++)
      bf[n] = *reinterpret_cast<const f16x8*>(
          Bl + ((wn * NFR + n) * 16 + (lane & 15)) * LROW + (lane >> 4) * 8);
#pragma unroll
    for (int m = 0; m < MFR; m++)
#pragma unroll
      for (int n = 0; n < NFR; n++)
        acc[m][n] = __builtin_amdgcn_mfma_f32_16x16x32_f16(af[m], bf[n], acc[m][n], 0, 0, 0);
    __syncthreads();
    if (s < 35) writeStage((s + 1) & 1);
  }

  if constexpr (OUTK == 0) {
#pragma unroll
    for (int m = 0; m < MFR; m++) {
      int ocb = (wm * MFR + m) * 16 + ((lane >> 4) << 2);
      float4 bv = *reinterpret_cast<const float4*>(bias + ocb);
#pragma unroll
      for (int n = 0; n < NFR; n++) {
        int pxl = (wn * NFR + n) * 16 + (lane & 15);
        int psy = pxl >> 5, psx = pxl & 31;
        size_t pixg = (size_t)b * HW_ + (size_t)(ty0 + psy) * W_ + tx0 + psx;
        ushort4 o;
        o.x = f2h(fmaxf(acc[m][n][0] + bv.x, 0.f));
        o.y = f2h(fmaxf(acc[m][n][1] + bv.y, 0.f));
        o.z = f2h(fmaxf(acc[m][n][2] + bv.z, 0.f));
        o.w = f2h(fmaxf(acc[m][n][3] + bv.w, 0.f));
        *reinterpret_cast<ushort4*>(obf + pixg * 128 + ocb) = o;
      }
    }
  } else {
#pragma unroll
    for (int m = 0; m < MFR; m++) {
      int ocb = (wm * MFR + m) * 16 + ((lane >> 4) << 2);
#pragma unroll
      for (int n = 0; n < NFR; n++) {
        int pxl = (wn * NFR + n) * 16 + (lane & 15);
        int psy = pxl >> 5, psx = pxl & 31;
        size_t pixg = (size_t)b * HW_ + (size_t)(ty0 + psy) * W_ + tx0 + psx;
#pragma unroll
        for (int j = 0; j < 4; j++) {
          int oc = ocb + j;
          if (oc < 18) of32[pixg * 18 + oc] = acc[m][n][j];
        }
      }
    }
  }
}

// ============ deformable conv as MFMA GEMM:
// per block: 64 pixels (16x4 tile) x 64 oc; K = 9 taps x 64 ch.
// Per tap: 256 thr bilinear-sample [64px][64ch] fp32->fp16 into LDS, then
// 2 K-steps of mfma_f32_16x16x32_f16; A (weights [k][oc][c] fp16) from global.
__global__ __launch_bounds__(256) void deform3(
    const float* __restrict__ hrh, const float* __restrict__ off,
    const unsigned short* __restrict__ wdh, float* __restrict__ out) {
  constexpr int LROW = 72;   // halves per samp row (64 + 8 pad), 144 B
  __shared__ unsigned short samp[64 * LROW];
  const int b = blockIdx.z;
  const int tile = blockIdx.x;                 // 400 tiles: 10 x * 40 y
  const int tx0 = (tile % 10) * 16, ty0 = (tile / 10) * 4;
  const int t = threadIdx.x, lane = t & 63, wid = t >> 6;
  const int wm = wid >> 1, wn = wid & 1;       // oc-half, px-half
  const int sp = t >> 2, sq = t & 3;           // sampling: pixel 0..63, ch-quarter
  const int px = tx0 + (sp & 15), py = ty0 + (sp >> 4);
  const int pixg = py * W_ + px;
  const float* hb = hrh + (size_t)b * HW_ * 64;
  const float* ob = off + ((size_t)b * HW_ + pixg) * 18;

  f32x4 acc[2][2];
#pragma unroll
  for (int m = 0; m < 2; m++)
#pragma unroll
    for (int n = 0; n < 2; n++) acc[m][n] = (f32x4)(0.f);

#pragma unroll 1
  for (int k = 0; k < 9; k++) {
    float dy = ob[2 * k];
    float dx = ob[2 * k + 1];
    float pyf = (float)(py + k / 3 - 1) + dy;
    float pxf = (float)(px + k % 3 - 1) + dx;
    float y0f = floorf(pyf), x0f = floorf(pxf);
    float wy = pyf - y0f, wx = pxf - x0f;
    int y0 = (int)y0f, x0i = (int)x0f;
    int y1 = y0 + 1, x1 = x0i + 1;
    bool vy0 = (y0 >= 0) & (y0 < H_), vy1 = (y1 >= 0) & (y1 < H_);
    bool vx0 = (x0i >= 0) & (x0i < W_), vx1 = (x1 >= 0) & (x1 < W_);
    int y0c = min(max(y0, 0), H_ - 1), y1c = min(max(y1, 0), H_ - 1);
    int x0c = min(max(x0i, 0), W_ - 1), x1c = min(max(x1, 0), W_ - 1);
    float w00 = (1.f - wy) * (1.f - wx) * ((vy0 & vx0) ? 1.f : 0.f);
    float w01 = (1.f - wy) * wx * ((vy0 & vx1) ? 1.f : 0.f);
    float w10 = wy * (1.f - wx) * ((vy1 & vx0) ? 1.f : 0.f);
    float w11 = wy * wx * ((vy1 & vx1) ? 1.f : 0.f);
    const float* p00 = hb + (size_t)(y0c * W_ + x0c) * 64 + sq * 16;
    const float* p01 = hb + (size_t)(y0c * W_ + x1c) * 64 + sq * 16;
    const float* p10 = hb + (size_t)(y1c * W_ + x0c) * 64 + sq * 16;
    const float* p11 = hb + (size_t)(y1c * W_ + x1c) * 64 + sq * 16;

    u16x8 lo, hi;
#pragma unroll
    for (int g = 0; g < 4; g++) {
      float4 a0 = *reinterpret_cast<const float4*>(p00 + g * 4);
      float4 a1 = *reinterpret_cast<const float4*>(p01 + g * 4);
      float4 a2 = *reinterpret_cast<const float4*>(p10 + g * 4);
      float4 a3 = *reinterpret_cast<const float4*>(p11 + g * 4);
      float s0 = w00 * a0.x + w01 * a1.x + w10 * a2.x + w11 * a3.x;
      float s1 = w00 * a0.y + w01 * a1.y + w10 * a2.y + w11 * a3.y;
      float s2 = w00 * a0.z + w01 * a1.z + w10 * a2.z + w11 * a3.z;
      float s3 = w00 * a0.w + w01 * a1.w + w10 * a2.w + w11 * a3.w;
      if (g < 2) {
        lo[g * 4 + 0] = f2h(s0); lo[g * 4 + 1] = f2h(s1);
        lo[g * 4 + 2] = f2h(s2); lo[g * 4 + 3] = f2h(s3);
      } else {
        hi[(g - 2) * 4 + 0] = f2h(s0); hi[(g - 2) * 4 + 1] = f2h(s1);
        hi[(g - 2) * 4 + 2] = f2h(s2); hi[(g - 2) * 4 + 3] = f2h(s3);
      }
    }
    __syncthreads();  // previous tap's MFMA reads done
    *reinterpret_cast<u16x8*>(&samp[sp * LROW + sq * 16]) = lo;
    *reinterpret_cast<u16x8*>(&samp[sp * LROW + sq * 16 + 8]) = hi;
    __syncthreads();  // samples visible

    const unsigned short* wk = wdh + (size_t)k * 4096;
#pragma unroll
    for (int kk = 0; kk < 2; kk++) {
      f16x8 af[2], bf[2];
#pragma unroll
      for (int m = 0; m < 2; m++)
        af[m] = *reinterpret_cast<const f16x8*>(
            wk + (size_t)(wm * 32 + m * 16 + (lane & 15)) * 64 + kk * 32 + (lane >> 4) * 8);
#pragma unroll
      for (int n = 0; n < 2; n++)
        bf[n] = *reinterpret_cast<const f16x8*>(
            &samp[(wn * 32 + n * 16 + (lane & 15)) * LROW + kk * 32 + (lane >> 4) * 8]);
#pragma unroll
      for (int m = 0; m < 2; m++)
#pragma unroll
        for (int n = 0; n < 2; n++)
          acc[m][n] = __builtin_amdgcn_mfma_f32_16x16x32_f16(af[m], bf[n], acc[m][n], 0, 0, 0);
    }
  }

#pragma unroll
  for (int m = 0; m < 2; m++)
#pragma unroll
    for (int n = 0; n < 2; n++) {
      int oc = wm * 32 + m * 16 + ((lane >> 4) << 2);
      int pxl = wn * 32 + n * 16 + (lane & 15);
      int gy = ty0 + (pxl >> 4), gx = tx0 + (pxl & 15);
      float* op = out + ((size_t)b * 64 + oc) * HW_ + (size_t)gy * W_ + gx;
      op[0] = acc[m][n][0];
      op[HW_] = acc[m][n][1];
      op[2 * HW_] = acc[m][n][2];
      op[3 * HW_] = acc[m][n][3];
    }
}

extern "C" void kernel_launch(void* const* d_in, const int* in_sizes, int n_in,
                              void* d_out, int out_size, void* d_ws, size_t ws_size,
                              hipStream_t stream) {
  const float* lr = (const float*)d_in[0];
  const float* hr = (const float*)d_in[1];
  const float* w1 = (const float*)d_in[2];
  const float* b1 = (const float*)d_in[3];
  const float* w2 = (const float*)d_in[4];
  const float* b2 = (const float*)d_in[5];
  const float* wo = (const float*)d_in[6];
  const float* wd = (const float*)d_in[7];
  float* out = (float*)d_out;

  char* w = (char*)d_ws;
  const size_t REG = 26214400;  // 4*25600*128*2B (= 4*25600*64*4B)
  unsigned short* cat = (unsigned short*)w;          // later reused as h2
  unsigned short* h2  = (unsigned short*)w;
  unsigned short* h1  = (unsigned short*)(w + REG);  // later reused as offsets
  float*          offb = (float*)(w + REG);
  float*          hrh = (float*)(w + 2 * REG);
  char* pD = w + 3 * REG;
  unsigned short* wt1b = (unsigned short*)pD;                    // 9*128*128*2
  unsigned short* wt2b = (unsigned short*)(pD + 294912);
  unsigned short* wtob = (unsigned short*)(pD + 2 * 294912);     // 9*32*128*2
  unsigned short* wdh  = (unsigned short*)(pD + 2 * 294912 + 73728);  // 9*64*64*2

  prep_inputs<<<dim3(400, 1, B_), 256, 0, stream>>>(lr, hr, cat, hrh);
  wprep_b<<<dim3((9 * 128 * 128 + 255) / 256), 256, 0, stream>>>(w1, wt1b, 128, 128, 128);
  wprep_b<<<dim3((9 * 128 * 128 + 255) / 256), 256, 0, stream>>>(w2, wt2b, 128, 128, 128);
  wprep_b<<<dim3((9 * 32 * 128 + 255) / 256), 256, 0, stream>>>(wo, wtob, 18, 32, 128);
  wprep_d<<<dim3((9 * 64 * 64 + 255) / 256), 256, 0, stream>>>(wd, wdh);

  convk<4, 4, 2, 2, 0><<<dim3(200, 1, B_), 256, 0, stream>>>(cat, wt1b, b1, h1, nullptr);
  convk<4, 4, 2, 2, 0><<<dim3(200, 1, B_), 256, 0, stream>>>(h1, wt2b, b2, h2, nullptr);
  convk<2, 4, 1, 4, 1><<<dim3(100, 1, B_), 256, 0, stream>>>(h2, wtob, nullptr, nullptr, offb);
  deform3<<<dim3(400, 1, B_), 256, 0, stream>>>(hrh, offb, wdh, out);
}

// Round 5
// 345.114 us; speedup vs baseline: 4.4295x; 1.4348x over previous
//
#include <hip/hip_runtime.h>

#define H_ 160
#define W_ 160
#define HW_ (H_*W_)
#define B_ 4

typedef _Float16 f16x8 __attribute__((ext_vector_type(8)));
typedef float f32x4 __attribute__((ext_vector_type(4)));
typedef unsigned short u16x8 __attribute__((ext_vector_type(8)));

__device__ __forceinline__ unsigned short f2h(float f) {
  _Float16 h = (_Float16)f;
  return *reinterpret_cast<unsigned short*>(&h);
}

// ============ prep: CHW fp32 (lr,hr) -> cat HWC fp16 [pix][128], hr HWC fp32 [pix][64]
__global__ __launch_bounds__(256) void prep_inputs(
    const float* __restrict__ lr, const float* __restrict__ hr,
    unsigned short* __restrict__ cat, float* __restrict__ hrh) {
  __shared__ float t0[64][65];
  const int b = blockIdx.z;
  const int px0 = blockIdx.x * 64;
  const int t = threadIdx.x;
  const int cc = t >> 6, lp = t & 63;

#pragma unroll
  for (int r = 0; r < 16; r++) {
    int c = r * 4 + cc;
    t0[lp][c] = lr[((size_t)b * 64 + c) * HW_ + px0 + lp];
  }
  __syncthreads();
  {
    int px = t >> 2, seg = t & 3;
    size_t pix = (size_t)b * HW_ + px0 + px;
    unsigned short* dst = cat + pix * 128 + seg * 16;
#pragma unroll
    for (int q = 0; q < 4; q++) {
      ushort4 o;
      o.x = f2h(t0[px][seg * 16 + q * 4 + 0]);
      o.y = f2h(t0[px][seg * 16 + q * 4 + 1]);
      o.z = f2h(t0[px][seg * 16 + q * 4 + 2]);
      o.w = f2h(t0[px][seg * 16 + q * 4 + 3]);
      *reinterpret_cast<ushort4*>(dst + q * 4) = o;
    }
  }
  __syncthreads();
#pragma unroll
  for (int r = 0; r < 16; r++) {
    int c = r * 4 + cc;
    t0[lp][c] = hr[((size_t)b * 64 + c) * HW_ + px0 + lp];
  }
  __syncthreads();
  {
    int px = t >> 2, seg = t & 3;
    size_t pix = (size_t)b * HW_ + px0 + px;
    unsigned short* dst = cat + pix * 128 + 64 + seg * 16;
    float* fdst = hrh + pix * 64 + seg * 16;
#pragma unroll
    for (int q = 0; q < 4; q++) {
      float v0 = t0[px][seg * 16 + q * 4 + 0];
      float v1 = t0[px][seg * 16 + q * 4 + 1];
      float v2 = t0[px][seg * 16 + q * 4 + 2];
      float v3 = t0[px][seg * 16 + q * 4 + 3];
      ushort4 o; o.x = f2h(v0); o.y = f2h(v1); o.z = f2h(v2); o.w = f2h(v3);
      *reinterpret_cast<ushort4*>(dst + q * 4) = o;
      float4 f; f.x = v0; f.y = v1; f.z = v2; f.w = v3;
      *reinterpret_cast<float4*>(fdst + q * 4) = f;
    }
  }
}

// ============ weight prep to MFMA-fragment-ready layout:
// w[oc][ic][3][3] fp32 -> out[frag][lane][8] fp16, frag = (k*4+cc)*(OCP/16)+mi
// fragment element: oc = mi*16+(lane&15), ic = cc*32+(lane>>4)*8+e
__global__ void wprep_frag(const float* __restrict__ w, unsigned short* __restrict__ out,
                           int OC, int OCP) {
  int i = blockIdx.x * 256 + threadIdx.x;
  int tot = 9 * OCP * 128;
  if (i >= tot) return;
  int frag = i >> 9, r = i & 511;
  int ln = r >> 3, e = r & 7;
  int nfrag = OCP >> 4;
  int k = frag / (4 * nfrag);
  int rem = frag % (4 * nfrag);
  int cc = rem / nfrag, mi = rem % nfrag;
  int oc = mi * 16 + (ln & 15);
  int ic = cc * 32 + (ln >> 4) * 8 + e;
  float v = (oc < OC) ? w[((size_t)(oc * 128 + ic)) * 9 + k] : 0.f;
  out[i] = f2h(v);
}

// deform weights: wd[oc][c][3][3] fp32 -> wdh[k][oc][c] fp16
__global__ void wprep_d(const float* __restrict__ w, unsigned short* __restrict__ out) {
  int i = blockIdx.x * 256 + threadIdx.x;
  if (i >= 9 * 64 * 64) return;
  int k = i / 4096;
  int r = i % 4096;
  int oc = r >> 6, c = r & 63;
  out[i] = f2h(w[((size_t)(oc * 64 + c)) * 9 + k]);
}

// ============ halo-LDS implicit-GEMM conv3x3 (barrier-free K-loop)
// Block: 32x4 px output tile (NT=128), OCB oc. Halo 6x34x128ch fp16 in LDS,
// XOR-swizzled (byte ^= (pix&7)<<4). A-fragments streamed from global (L2).
template<int OCB, int WM, int WN, int OUTK>
__global__ __launch_bounds__(256) void convh(
    const unsigned short* __restrict__ xin,   // [b][25600][128] fp16 HWC
    const unsigned short* __restrict__ wf,    // fragment-ready weights
    const float* __restrict__ bias,
    unsigned short* __restrict__ obf, float* __restrict__ of32) {
  constexpr int MFR = OCB / (WM * 16);
  constexpr int NFR = 128 / (WN * 16);
  constexpr int NFRAG = OCB / 16;
  __shared__ unsigned short lds[26112];   // 52224 B: 6*34 px * 256 B

  const int t = threadIdx.x, lane = t & 63, wid = t >> 6;
  const int wm = wid / WN, wn = wid % WN;
  const int b = blockIdx.z;
  const int tx0 = (blockIdx.x % 5) * 32;
  const int ty0 = (blockIdx.x / 5) * 4;
  const size_t xbase = (size_t)b * HW_ * 128;

  // ---- halo load: 6 x 34 pixels x 16 chunks(16B) = 3264 chunks
#pragma unroll
  for (int i = 0; i < 13; i++) {
    int c = t + i * 256;
    if (c < 3264) {
      int hy = c / 544, rem = c % 544;
      int hx = rem >> 4, cq = rem & 15;
      int gy = ty0 - 1 + hy, gx = tx0 - 1 + hx;
      uint4 v;
      if (gy >= 0 && gy < H_ && gx >= 0 && gx < W_) {
        v = *reinterpret_cast<const uint4*>(
            xin + xbase + ((size_t)(gy * W_ + gx) * 128 + cq * 8));
      } else {
        v.x = v.y = v.z = v.w = 0u;
      }
      int p = hy * 34 + hx;
      int byt = (p * 256 + cq * 16) ^ ((p & 7) << 4);
      *reinterpret_cast<uint4*>(reinterpret_cast<char*>(lds) + byt) = v;
    }
  }
  __syncthreads();

  f32x4 acc[MFR][NFR];
#pragma unroll
  for (int m = 0; m < MFR; m++)
#pragma unroll
    for (int n = 0; n < NFR; n++) acc[m][n] = (f32x4)(0.f);

  int p0[NFR];
#pragma unroll
  for (int n = 0; n < NFR; n++) {
    int pxl = (wn * NFR + n) * 16 + (lane & 15);
    p0[n] = ((pxl >> 5) + 1) * 34 + (pxl & 31) + 1;
  }
  const int chb = (lane >> 4) * 16;
  const unsigned short* wfb = wf + (size_t)(wm * MFR) * 512 + lane * 8;

  // ---- 36-stage K-loop, no barriers
  for (int k = 0; k < 9; k++) {
    const int kofs = (k / 3 - 1) * 34 + (k % 3 - 1);
#pragma unroll
    for (int cc = 0; cc < 4; cc++) {
      f16x8 af[MFR], bf[NFR];
#pragma unroll
      for (int m = 0; m < MFR; m++)
        af[m] = *reinterpret_cast<const f16x8*>(
            wfb + (size_t)((k * 4 + cc) * NFRAG + m) * 512);
#pragma unroll
      for (int n = 0; n < NFR; n++) {
        int p = p0[n] + kofs;
        int byt = (p * 256 + cc * 64 + chb) ^ ((p & 7) << 4);
        bf[n] = *reinterpret_cast<const f16x8*>(
            reinterpret_cast<const char*>(lds) + byt);
      }
#pragma unroll
      for (int m = 0; m < MFR; m++)
#pragma unroll
        for (int n = 0; n < NFR; n++)
          acc[m][n] = __builtin_amdgcn_mfma_f32_16x16x32_f16(af[m], bf[n], acc[m][n], 0, 0, 0);
    }
  }

  if constexpr (OUTK == 0) {
    // transpose via LDS -> fully coalesced HWC stores
    __syncthreads();
#pragma unroll
    for (int m = 0; m < MFR; m++) {
      int ocb = (wm * MFR + m) * 16 + ((lane >> 4) << 2);
      float4 bv = *reinterpret_cast<const float4*>(bias + ocb);
#pragma unroll
      for (int n = 0; n < NFR; n++) {
        int px = (wn * NFR + n) * 16 + (lane & 15);
        ushort4 o;
        o.x = f2h(fmaxf(acc[m][n][0] + bv.x, 0.f));
        o.y = f2h(fmaxf(acc[m][n][1] + bv.y, 0.f));
        o.z = f2h(fmaxf(acc[m][n][2] + bv.z, 0.f));
        o.w = f2h(fmaxf(acc[m][n][3] + bv.w, 0.f));
        int byt = (px * 256 + ocb * 2) ^ ((px & 7) << 4);
        *reinterpret_cast<ushort4*>(reinterpret_cast<char*>(lds) + byt) = o;
      }
    }
    __syncthreads();
    {
      int pxl = t >> 3, c2 = (t & 7) * 2;
#pragma unroll
      for (int i = 0; i < 4; i++) {
        int px = pxl + i * 32;
        int swz = (px & 7) << 4;
        uint4 v0 = *reinterpret_cast<uint4*>(
            reinterpret_cast<char*>(lds) + ((px * 256 + c2 * 16) ^ swz));
        uint4 v1 = *reinterpret_cast<uint4*>(
            reinterpret_cast<char*>(lds) + ((px * 256 + c2 * 16 + 16) ^ swz));
        int gy = ty0 + (px >> 5), gx = tx0 + (px & 31);
        unsigned short* dst = obf + ((size_t)b * HW_ + (size_t)gy * W_ + gx) * 128 + c2 * 8;
        *reinterpret_cast<uint4*>(dst) = v0;
        *reinterpret_cast<uint4*>(dst + 8) = v1;
      }
    }
  } else {
#pragma unroll
    for (int m = 0; m < MFR; m++) {
      int ocb = (wm * MFR + m) * 16 + ((lane >> 4) << 2);
#pragma unroll
      for (int n = 0; n < NFR; n++) {
        int px = (wn * NFR + n) * 16 + (lane & 15);
        int gy = ty0 + (px >> 5), gx = tx0 + (px & 31);
        size_t pixg = (size_t)b * HW_ + (size_t)gy * W_ + gx;
#pragma unroll
        for (int j = 0; j < 4; j++) {
          int oc = ocb + j;
          if (oc < 18) of32[pixg * 18 + oc] = acc[m][n][j];
        }
      }
    }
  }
}

// ============ deformable conv as MFMA GEMM (unchanged from round 3)
__global__ __launch_bounds__(256) void deform3(
    const float* __restrict__ hrh, const float* __restrict__ off,
    const unsigned short* __restrict__ wdh, float* __restrict__ out) {
  constexpr int LROW = 72;
  __shared__ unsigned short samp[64 * LROW];
  const int b = blockIdx.z;
  const int tile = blockIdx.x;
  const int tx0 = (tile % 10) * 16, ty0 = (tile / 10) * 4;
  const int t = threadIdx.x, lane = t & 63, wid = t >> 6;
  const int wm = wid >> 1, wn = wid & 1;
  const int sp = t >> 2, sq = t & 3;
  const int px = tx0 + (sp & 15), py = ty0 + (sp >> 4);
  const int pixg = py * W_ + px;
  const float* hb = hrh + (size_t)b * HW_ * 64;
  const float* ob = off + ((size_t)b * HW_ + pixg) * 18;

  f32x4 acc[2][2];
#pragma unroll
  for (int m = 0; m < 2; m++)
#pragma unroll
    for (int n = 0; n < 2; n++) acc[m][n] = (f32x4)(0.f);

#pragma unroll 1
  for (int k = 0; k < 9; k++) {
    float dy = ob[2 * k];
    float dx = ob[2 * k + 1];
    float pyf = (float)(py + k / 3 - 1) + dy;
    float pxf = (float)(px + k % 3 - 1) + dx;
    float y0f = floorf(pyf), x0f = floorf(pxf);
    float wy = pyf - y0f, wx = pxf - x0f;
    int y0 = (int)y0f, x0i = (int)x0f;
    int y1 = y0 + 1, x1 = x0i + 1;
    bool vy0 = (y0 >= 0) & (y0 < H_), vy1 = (y1 >= 0) & (y1 < H_);
    bool vx0 = (x0i >= 0) & (x0i < W_), vx1 = (x1 >= 0) & (x1 < W_);
    int y0c = min(max(y0, 0), H_ - 1), y1c = min(max(y1, 0), H_ - 1);
    int x0c = min(max(x0i, 0), W_ - 1), x1c = min(max(x1, 0), W_ - 1);
    float w00 = (1.f - wy) * (1.f - wx) * ((vy0 & vx0) ? 1.f : 0.f);
    float w01 = (1.f - wy) * wx * ((vy0 & vx1) ? 1.f : 0.f);
    float w10 = wy * (1.f - wx) * ((vy1 & vx0) ? 1.f : 0.f);
    float w11 = wy * wx * ((vy1 & vx1) ? 1.f : 0.f);
    const float* p00 = hb + (size_t)(y0c * W_ + x0c) * 64 + sq * 16;
    const float* p01 = hb + (size_t)(y0c * W_ + x1c) * 64 + sq * 16;
    const float* p10 = hb + (size_t)(y1c * W_ + x0c) * 64 + sq * 16;
    const float* p11 = hb + (size_t)(y1c * W_ + x1c) * 64 + sq * 16;

    u16x8 lo, hi;
#pragma unroll
    for (int g = 0; g < 4; g++) {
      float4 a0 = *reinterpret_cast<const float4*>(p00 + g * 4);
      float4 a1 = *reinterpret_cast<const float4*>(p01 + g * 4);
      float4 a2 = *reinterpret_cast<const float4*>(p10 + g * 4);
      float4 a3 = *reinterpret_cast<const float4*>(p11 + g * 4);
      float s0 = w00 * a0.x + w01 * a1.x + w10 * a2.x + w11 * a3.x;
      float s1 = w00 * a0.y + w01 * a1.y + w10 * a2.y + w11 * a3.y;
      float s2 = w00 * a0.z + w01 * a1.z + w10 * a2.z + w11 * a3.z;
      float s3 = w00 * a0.w + w01 * a1.w + w10 * a2.w + w11 * a3.w;
      if (g < 2) {
        lo[g * 4 + 0] = f2h(s0); lo[g * 4 + 1] = f2h(s1);
        lo[g * 4 + 2] = f2h(s2); lo[g * 4 + 3] = f2h(s3);
      } else {
        hi[(g - 2) * 4 + 0] = f2h(s0); hi[(g - 2) * 4 + 1] = f2h(s1);
        hi[(g - 2) * 4 + 2] = f2h(s2); hi[(g - 2) * 4 + 3] = f2h(s3);
      }
    }
    __syncthreads();
    *reinterpret_cast<u16x8*>(&samp[sp * LROW + sq * 16]) = lo;
    *reinterpret_cast<u16x8*>(&samp[sp * LROW + sq * 16 + 8]) = hi;
    __syncthreads();

    const unsigned short* wk = wdh + (size_t)k * 4096;
#pragma unroll
    for (int kk = 0; kk < 2; kk++) {
      f16x8 af[2], bf[2];
#pragma unroll
      for (int m = 0; m < 2; m++)
        af[m] = *reinterpret_cast<const f16x8*>(
            wk + (size_t)(wm * 32 + m * 16 + (lane & 15)) * 64 + kk * 32 + (lane >> 4) * 8);
#pragma unroll
      for (int n = 0; n < 2; n++)
        bf[n] = *reinterpret_cast<const f16x8*>(
            &samp[(wn * 32 + n * 16 + (lane & 15)) * LROW + kk * 32 + (lane >> 4) * 8]);
#pragma unroll
      for (int m = 0; m < 2; m++)
#pragma unroll
        for (int n = 0; n < 2; n++)
          acc[m][n] = __builtin_amdgcn_mfma_f32_16x16x32_f16(af[m], bf[n], acc[m][n], 0, 0, 0);
    }
  }

#pragma unroll
  for (int m = 0; m < 2; m++)
#pragma unroll
    for (int n = 0; n < 2; n++) {
      int oc = wm * 32 + m * 16 + ((lane >> 4) << 2);
      int pxl = wn * 32 + n * 16 + (lane & 15);
      int gy = ty0 + (pxl >> 4), gx = tx0 + (pxl & 15);
      float* op = out + ((size_t)b * 64 + oc) * HW_ + (size_t)gy * W_ + gx;
      op[0] = acc[m][n][0];
      op[HW_] = acc[m][n][1];
      op[2 * HW_] = acc[m][n][2];
      op[3 * HW_] = acc[m][n][3];
    }
}

extern "C" void kernel_launch(void* const* d_in, const int* in_sizes, int n_in,
                              void* d_out, int out_size, void* d_ws, size_t ws_size,
                              hipStream_t stream) {
  const float* lr = (const float*)d_in[0];
  const float* hr = (const float*)d_in[1];
  const float* w1 = (const float*)d_in[2];
  const float* b1 = (const float*)d_in[3];
  const float* w2 = (const float*)d_in[4];
  const float* b2 = (const float*)d_in[5];
  const float* wo = (const float*)d_in[6];
  const float* wd = (const float*)d_in[7];
  float* out = (float*)d_out;

  char* w = (char*)d_ws;
  const size_t REG = 26214400;  // 4*25600*128*2B (= 4*25600*64*4B)
  unsigned short* cat = (unsigned short*)w;          // later reused as h2
  unsigned short* h2  = (unsigned short*)w;
  unsigned short* h1  = (unsigned short*)(w + REG);  // later reused as offsets
  float*          offb = (float*)(w + REG);
  float*          hrh = (float*)(w + 2 * REG);
  char* pD = w + 3 * REG;
  unsigned short* wf1 = (unsigned short*)pD;                     // 9*128*128*2
  unsigned short* wf2 = (unsigned short*)(pD + 294912);
  unsigned short* wfo = (unsigned short*)(pD + 2 * 294912);      // 9*32*128*2
  unsigned short* wdh = (unsigned short*)(pD + 2 * 294912 + 73728);  // 9*64*64*2

  prep_inputs<<<dim3(400, 1, B_), 256, 0, stream>>>(lr, hr, cat, hrh);
  wprep_frag<<<dim3((9 * 128 * 128 + 255) / 256), 256, 0, stream>>>(w1, wf1, 128, 128);
  wprep_frag<<<dim3((9 * 128 * 128 + 255) / 256), 256, 0, stream>>>(w2, wf2, 128, 128);
  wprep_frag<<<dim3((9 * 32 * 128 + 255) / 256), 256, 0, stream>>>(wo, wfo, 18, 32);
  wprep_d<<<dim3((9 * 64 * 64 + 255) / 256), 256, 0, stream>>>(wd, wdh);

  convh<128, 2, 2, 0><<<dim3(200, 1, B_), 256, 0, stream>>>(cat, wf1, b1, h1, nullptr);
  convh<128, 2, 2, 0><<<dim3(200, 1, B_), 256, 0, stream>>>(h1, wf2, b2, h2, nullptr);
  convh<32, 1, 4, 1><<<dim3(200, 1, B_), 256, 0, stream>>>(h2, wfo, nullptr, nullptr, offb);
  deform3<<<dim3(400, 1, B_), 256, 0, stream>>>(hrh, offb, wdh, out);
}